// Round 5
// baseline (472.651 us; speedup 1.0000x reference)
//
#include <hip/hip_runtime.h>

// x[2,8,540,960] f32, filt[16,8] f32, scale=3 (runtime), out[2,8,1620,2880] f32.
#define Hh 540
#define Ww 960
#define OHh 1620
#define OWw 2880
#define OW4 720   // float4 groups per output row
#define RPB 4     // output rows per block (1620 % 4 == 0)

typedef float floatx4 __attribute__((ext_vector_type(4)));

// ---- Setup: build phase tables once into d_ws (re-run every launch; d_ws is
// re-poisoned before every timed call). rtab[1620] at ws+0, ctab[2880] at
// ws+16KB. Entry: {f32 w, u32 meta = pos(10b) | frac<<10 | sat<<14 | (ix+8)<<15}.
// Row w = s_sum[frac]/4096 ; col w = s_sum[frac]. Replicates
// ref=int(i*16384/scale); integer=ref>>4; frac=ref&15 exactly (u32 math).
__global__ __launch_bounds__(256) void vtm_setup(
    const float* __restrict__ filt, const int* __restrict__ scale_p,
    uint2* __restrict__ ws)
{
    __shared__ float s_f[16][8];
    __shared__ float s_sum[16];
    const int tid = threadIdx.x;
    if (tid < 128) ((float*)s_f)[tid] = filt[tid];
    __syncthreads();
    if (tid < 16) {
        float s = 0.f;
        #pragma unroll
        for (int k = 0; k < 8; ++k) s += s_f[tid][k];   // same order as before (bit-identical)
        s_sum[tid] = s;
    }
    __syncthreads();
    const unsigned scale = (unsigned)*scale_p;
    const float inv = 1.0f / 4096.0f;
    uint2* rtab = ws;
    uint2* ctab = ws + 2048;
    for (int i = tid; i < OHh; i += 256) {
        const unsigned ref = ((unsigned)i * 16384u) / scale;
        const int ii = (int)(ref >> 4);
        const unsigned f = ref & 15u;
        const int lo = min(max(ii - 3, 0), Hh - 1);
        const int hi = min(max(ii + 4, 0), Hh - 1);
        const int iic = min(max(ii, -8), 2039);   // ix only consumed when !sat (then small)
        const unsigned meta = (unsigned)lo | (f << 10) | ((lo == hi) ? 0x4000u : 0u)
                            | ((unsigned)(iic + 8) << 15);
        rtab[i] = make_uint2(__float_as_uint(s_sum[f] * inv), meta);
    }
    for (int i = tid; i < OWw; i += 256) {
        const unsigned ref = ((unsigned)i * 16384u) / scale;
        const int ii = (int)(ref >> 4);
        const unsigned f = ref & 15u;
        const int lo = min(max(ii - 3, 0), Ww - 1);
        const int hi = min(max(ii + 4, 0), Ww - 1);
        const int iic = min(max(ii, -8), 2039);
        const unsigned meta = (unsigned)lo | (f << 10) | ((lo == hi) ? 0x4000u : 0u)
                            | ((unsigned)(iic + 8) << 15);
        ctab[i] = make_uint2(__float_as_uint(s_sum[f]), meta);
    }
}

// ---- Main: block = (4 output rows, one bc image). Hot path per float4:
// one 32B coalesced table read (L1-resident, shared by all blocks), 4
// broadcast x loads (L1), 8 mults, 1 nontemporal 16B store. No divisions.
__global__ __launch_bounds__(256) void vtm_main(
    const float* __restrict__ x, const float* __restrict__ filt,
    const uint2* __restrict__ ws, float* __restrict__ out)
{
    __shared__ float s_f[16][8];   // only used by rare non-saturated lanes
    const int tid = threadIdx.x;
    if (tid < 128) ((float*)s_f)[tid] = filt[tid];
    __syncthreads();

    const unsigned oy0 = blockIdx.x * RPB;
    const unsigned bc  = blockIdx.y;
    const float* __restrict__ xp = x + (size_t)bc * (Hh * Ww);
    float* __restrict__ op = out + (size_t)bc * ((size_t)OHh * OWw);
    const uint2* rtab  = ws;
    const uint4* ctab4 = (const uint4*)(ws + 2048);

    float wyi[RPB]; unsigned rm[RPB];
    #pragma unroll
    for (int r = 0; r < RPB; ++r) {          // uniform → scalarized by compiler
        const uint2 t = rtab[oy0 + r];
        wyi[r] = __uint_as_float(t.x);
        rm[r]  = t.y;
    }
    const unsigned rall = rm[0] & rm[1] & rm[2] & rm[3];

    for (unsigned g = (unsigned)tid; g < OW4; g += 256u) {
        const uint4 ta = ctab4[2u * g];       // cols 4g,4g+1
        const uint4 tb = ctab4[2u * g + 1u];  // cols 4g+2,4g+3
        const float wx0 = __uint_as_float(ta.x), wx1 = __uint_as_float(ta.z);
        const float wx2 = __uint_as_float(tb.x), wx3 = __uint_as_float(tb.z);
        const unsigned cm0 = ta.y, cm1 = ta.w, cm2 = tb.y, cm3 = tb.w;

        if (rall & cm0 & cm1 & cm2 & cm3 & 0x4000u) {
            // Fully clamp-collapsed 4x4 patch: val = x[r0][c0]*sum(cw)*sum(ch)/4096.
            #pragma unroll
            for (int r = 0; r < RPB; ++r) {
                const float* __restrict__ rp = xp + (rm[r] & 1023u) * Ww;
                const float wr = wyi[r];
                floatx4 v = { rp[cm0 & 1023u] * wx0 * wr,
                              rp[cm1 & 1023u] * wx1 * wr,
                              rp[cm2 & 1023u] * wx2 * wr,
                              rp[cm3 & 1023u] * wx3 * wr };
                __builtin_nontemporal_store(v,
                    reinterpret_cast<floatx4*>(op + (size_t)(oy0 + r) * OWw + 4u * g));
            }
        } else {
            // Rare (oy<2 or ox<3 for scale=3): per-element, full 8x8 MAC when needed.
            const unsigned cms[4] = {cm0, cm1, cm2, cm3};
            const float    wxs[4] = {wx0, wx1, wx2, wx3};
            #pragma unroll
            for (int r = 0; r < RPB; ++r) {
                const unsigned rmr = rm[r];
                const int r0 = (int)(rmr & 1023u);
                const int fy = (int)((rmr >> 10) & 15u);
                const int iy = (int)((rmr >> 15) & 2047u) - 8;
                float vals[4];
                #pragma unroll
                for (int u = 0; u < 4; ++u) {
                    const unsigned cmu = cms[u];
                    if (rmr & cmu & 0x4000u) {
                        vals[u] = xp[r0 * Ww + (int)(cmu & 1023u)] * wxs[u] * wyi[r];
                    } else {
                        const int fx = (int)((cmu >> 10) & 15u);
                        const int ix = (int)((cmu >> 15) & 2047u) - 8;
                        float acc = 0.f;
                        #pragma unroll
                        for (int j = 0; j < 8; ++j) {
                            const int ry = min(max(iy + j - 3, 0), Hh - 1);
                            const float* __restrict__ rp2 = xp + ry * Ww;
                            float h = 0.f;
                            #pragma unroll
                            for (int k = 0; k < 8; ++k) {
                                const int cx = min(max(ix + k - 3, 0), Ww - 1);
                                h = fmaf(s_f[fx][k], rp2[cx], h);
                            }
                            acc = fmaf(s_f[fy][j], h, acc);
                        }
                        vals[u] = acc * (1.0f / 4096.0f);
                    }
                }
                floatx4 v = { vals[0], vals[1], vals[2], vals[3] };
                __builtin_nontemporal_store(v,
                    reinterpret_cast<floatx4*>(op + (size_t)(oy0 + r) * OWw + 4u * g));
            }
        }
    }
}

extern "C" void kernel_launch(void* const* d_in, const int* in_sizes, int n_in,
                              void* d_out, int out_size, void* d_ws, size_t ws_size,
                              hipStream_t stream) {
    const float* x       = (const float*)d_in[0];
    const float* filt    = (const float*)d_in[1];
    const int*   scale_p = (const int*)d_in[2];
    float* out = (float*)d_out;
    uint2* ws  = (uint2*)d_ws;     // needs ~40 KB; ws is ~1.2 GB
    vtm_setup<<<dim3(1), dim3(256), 0, stream>>>(filt, scale_p, ws);
    vtm_main <<<dim3(OHh / RPB, 16), dim3(256), 0, stream>>>(x, filt, ws, out);
}

// Round 6
// 319.711 us; speedup vs baseline: 1.4784x; 1.4784x over previous
//
#include <hip/hip_runtime.h>

// x[2,8,540,960] f32, filt[16,8] f32, scale=3 (runtime), out[2,8,1620,2880] f32.
#define Hh 540
#define Ww 960
#define OHh 1620
#define OWw 2880
#define OW4 720          // float4 groups per output row
#define RPB 30           // rows per block; 1620 = 54 * 30

typedef float floatx4 __attribute__((ext_vector_type(4)));

// Thread owns 4 fixed output columns; loops over RPB rows. All row-invariant
// work (column phases, x loads, horizontal collapse) hoisted out of the row
// loop. Steady-state row body: 4 mults + one coalesced 16B store.
__global__ __launch_bounds__(256) void vtm_upsample(
    const float* __restrict__ x, const float* __restrict__ filt,
    const int* __restrict__ scale_p, float* __restrict__ out)
{
    __shared__ float s_f[16][8];
    __shared__ float s_sum[16];
    __shared__ float s_wy[RPB];      // s_sum[fy] * (1/4096) per row
    __shared__ unsigned s_rm[RPB];   // r0 | fy<<10 | sat<<14 | (iy+8)<<15

    const int tid = threadIdx.x;
    const unsigned scale = (unsigned)*scale_p;
    const float inv = 1.0f / 4096.0f;
    const unsigned oy0 = blockIdx.y * RPB;

    if (tid < 128) ((float*)s_f)[tid] = filt[tid];
    __syncthreads();
    if (tid < 16) {
        float s = 0.f;
        #pragma unroll
        for (int k = 0; k < 8; ++k) s += s_f[tid][k];  // same order as prior passing rounds
        s_sum[tid] = s;
    }
    __syncthreads();
    if (tid < RPB) {
        // Row phase: ref=int(oy*16384/scale); integer=ref>>4; frac=ref&15 (u32 math).
        const unsigned oy = oy0 + (unsigned)tid;
        const unsigned ref = (oy * 16384u) / scale;
        const int ii = (int)(ref >> 4);
        const unsigned f = ref & 15u;
        const int lo = min(max(ii - 3, 0), Hh - 1);
        const int hi = min(max(ii + 4, 0), Hh - 1);
        s_rm[tid] = (unsigned)lo | (f << 10) | ((lo == hi) ? 0x4000u : 0u)
                  | ((unsigned)(min(max(ii, -8), 4095) + 8) << 15);
        s_wy[tid] = s_sum[f] * inv;
    }
    __syncthreads();

    const unsigned bc = blockIdx.z;
    const float* __restrict__ xp = x + (size_t)bc * (Hh * Ww);
    float* __restrict__ op = out + (size_t)bc * ((size_t)OHh * OWw);
    const unsigned g = blockIdx.x * 256u + (unsigned)tid;
    if (g >= OW4) return;            // no barriers below this point

    // ---- Row-invariant column setup (once per thread) ----
    float vx[4];                     // x-row-collapsed value * wx, for saturated rows (r0 = H-1)
    int   ixs[4], fxs[4];
    {
        const float* __restrict__ rp = xp + (Hh - 1) * Ww;
        #pragma unroll
        for (int u = 0; u < 4; ++u) {
            const unsigned ox = 4u * g + (unsigned)u;
            const unsigned refx = (ox * 16384u) / scale;
            const int ix = (int)(refx >> 4);
            const int fx = (int)(refx & 15u);
            ixs[u] = ix; fxs[u] = fx;
            const int c0 = min(max(ix - 3, 0), Ww - 1);
            const int c7 = min(max(ix + 4, 0), Ww - 1);
            if (c0 == c7) {
                vx[u] = rp[c0] * s_sum[fx];            // horizontal 8-tap collapses
            } else {
                float h = 0.f;                          // rare: ox<3 — real horizontal MAC on row H-1
                #pragma unroll
                for (int k = 0; k < 8; ++k) {
                    const int cx = min(max(ix + k - 3, 0), Ww - 1);
                    h = fmaf(s_f[fx][k], rp[cx], h);
                }
                vx[u] = h;
            }
        }
    }

    float* o0 = op + (size_t)oy0 * OWw + 4u * g;

    // Leading non-saturated rows (only blocks at oy0==0; monotone, so a prefix).
    int rs = 0;
    while (rs < RPB && !(s_rm[rs] & 0x4000u)) ++rs;
    for (int r = 0; r < rs; ++r) {
        const unsigned rm = s_rm[r];
        const int fy = (int)((rm >> 10) & 15u);
        const int iy = (int)((rm >> 15) & 8191u) - 8;
        float vals[4];
        #pragma unroll
        for (int u = 0; u < 4; ++u) {
            float acc = 0.f;
            #pragma unroll
            for (int j = 0; j < 8; ++j) {
                const int ry = min(max(iy + j - 3, 0), Hh - 1);
                const float* __restrict__ rp2 = xp + ry * Ww;
                float h = 0.f;
                #pragma unroll
                for (int k = 0; k < 8; ++k) {
                    const int cx = min(max(ixs[u] + k - 3, 0), Ww - 1);
                    h = fmaf(s_f[fxs[u]][k], rp2[cx], h);
                }
                acc = fmaf(s_f[fy][j], h, acc);
            }
            vals[u] = acc * inv;
        }
        floatx4 v = { vals[0], vals[1], vals[2], vals[3] };
        *reinterpret_cast<floatx4*>(o0 + (size_t)r * OWw) = v;
    }

    // ---- Saturated rows: val = vx * wy — 4 mults + 1 store per row ----
    for (int r = rs; r < RPB; ++r) {
        const float wy = s_wy[r];
        floatx4 v = { vx[0] * wy, vx[1] * wy, vx[2] * wy, vx[3] * wy };
        *reinterpret_cast<floatx4*>(o0 + (size_t)r * OWw) = v;
    }
}

extern "C" void kernel_launch(void* const* d_in, const int* in_sizes, int n_in,
                              void* d_out, int out_size, void* d_ws, size_t ws_size,
                              hipStream_t stream) {
    const float* x       = (const float*)d_in[0];
    const float* filt    = (const float*)d_in[1];
    const int*   scale_p = (const int*)d_in[2];
    float* out = (float*)d_out;
    dim3 grid(3, OHh / RPB, 16), block(256);   // 3 col-tiles x 54 row-chunks x 16 images
    vtm_upsample<<<grid, block, 0, stream>>>(x, filt, scale_p, out);
}